// Round 2
// baseline (1989.900 us; speedup 1.0000x reference)
//
#include <hip/hip_runtime.h>
#include <hip/hip_bf16.h>

#define BB 64
#define LLEN 512
#define HH 400
#define L1 513
#define TT 32832      // BB*L1
#define NE 768        // enh(256)|enm(256)|elh(128)|elm(128)
#define KP 16640      // 16384 bilinear + 128 Wl + 128 Wr (phase-permuted)
#define PHW 4160      // per-phase k' width: 130 d-slices * 32

typedef __attribute__((ext_vector_type(4))) float f32x4;
typedef __attribute__((ext_vector_type(8))) short bf16x8;
typedef unsigned int u32;
typedef __attribute__((address_space(1))) const u32* gptr_t;
typedef __attribute__((address_space(3))) u32* sptr_t;

// round-to-nearest-even f32 -> bf16 (finite inputs)
__device__ inline unsigned short f2bf(float x){
  unsigned u = __float_as_uint(x);
  unsigned r = (u + 0x7fffu + ((u >> 16) & 1u)) >> 16;
  return (unsigned short)r;
}
__device__ inline unsigned pk2(float a, float b){
  return (unsigned)f2bf(a) | ((unsigned)f2bf(b) << 16);
}

// ---------------- init: labels1 output, gold gather idx, label buf, zero nll ----
__global__ __launch_bounds__(256) void k_init(const int* eh, const int* el, float* out,
                                              int* idx, int* labbuf){
  int t = blockIdx.x*256 + threadIdx.x;
  if (t < TT){
    int b = t / L1, m = t - b*L1;
    int lab = m ? el[b*LLEN + m - 1] : 0;
    int hd  = m ? eh[b*LLEN + m - 1] : 0;
    out[65536 + t] = (float)lab;
    labbuf[t] = lab;
    idx[t] = b*L1 + hd;
  }
  if (blockIdx.x == 0 && threadIdx.x < 2) out[98368 + threadIdx.x] = 0.f;
}

// ---------------- build concatenated encoder weights ----------------
__global__ __launch_bounds__(256) void k_wcat(const float* Wenh,const float* benh,
    const float* Wenm,const float* benm,const float* Welh,const float* belh,
    const float* Welm,const float* belm,float* Wcat,float* bcat){
  int g = blockIdx.x*256 + threadIdx.x;
  if (g < HH*NE){
    int k = g / NE, n = g - k*NE;
    float v;
    if (n < 256) v = Wenh[k*256 + n];
    else if (n < 512) v = Wenm[k*256 + n - 256];
    else if (n < 640) v = Welh[k*128 + n - 512];
    else v = Welm[k*128 + n - 640];
    Wcat[g] = v;
  }
  if (g < NE){
    float v;
    if (g < 256) v = benh[g];
    else if (g < 512) v = benm[g - 256];
    else if (g < 640) v = belh[g - 512];
    else v = belm[g - 640];
    bcat[g] = v;
  }
}

// ------------- build WtTp[n][k'] bf16, K phase-permuted: k' = p*4160 + d*32 + j,
// (p,d,j): d<128 -> U[n][d][32p+j]; d==128 -> Wl[n][32p+j]; d==129 -> Wr[n][32p+j]
__global__ __launch_bounds__(256) void k_wtt(const float* lblU, const float* Wl,
    const float* Wr, unsigned short* WtTp){
  int n = blockIdx.y;
  int kp = blockIdx.x*256 + threadIdx.x;
  if (kp >= KP) return;
  int p = kp / PHW; int q2 = kp - p*PHW; int dd = q2 >> 5; int j = q2 & 31; int e = p*32 + j;
  float v;
  if (dd < 128) v = lblU[(size_t)n*16384 + dd*128 + e];
  else if (dd == 128) v = Wl[n*128 + e];
  else v = Wr[n*128 + e];
  WtTp[(size_t)n*KP + kp] = f2bf(v);
}

#define INNER8(AS, BS) \
  _Pragma("unroll") \
  for (int kk = 0; kk < 8; kk++){ \
    float4 a0 = *(const float4*)&AS[kk][ty*8]; \
    float4 a1 = *(const float4*)&AS[kk][ty*8+4]; \
    float4 b0 = *(const float4*)&BS[kk][tx*8]; \
    float4 b1 = *(const float4*)&BS[kk][tx*8+4]; \
    float avv[8] = {a0.x,a0.y,a0.z,a0.w,a1.x,a1.y,a1.z,a1.w}; \
    float bvv[8] = {b0.x,b0.y,b0.z,b0.w,b1.x,b1.y,b1.z,b1.w}; \
    _Pragma("unroll") \
    for (int ii = 0; ii < 8; ii++) \
      _Pragma("unroll") \
      for (int jj = 0; jj < 8; jj++) \
        c_[ii][jj] += avv[ii]*bvv[jj]; \
  }

// ---------------- K1: E = elu([sentinel;mb] @ Wcat + bcat), fp32 128x128x8 tile ----
__global__ __launch_bounds__(256) void k_enc(const float* mb, const float* sent,
    const float* Wcat, const float* bcat, float* E){
  __shared__ float As[8][132];
  __shared__ float Bs[8][132];
  int tid = threadIdx.x, tx = tid & 15, ty = tid >> 4;
  int Mb = blockIdx.x * 128, n0 = blockIdx.y * 128;
  int ar = tid >> 1, akc = (tid & 1) * 4;
  int row = Mb + ar;
  bool aval = row < TT;
  const float* ap = sent;
  if (aval){
    int br = row / L1, mr = row - br*L1;
    if (mr) ap = mb + (size_t)(br*LLEN + mr - 1)*HH;
  }
  int bkr = tid >> 5, bnc = (tid & 31) * 4;
  float c_[8][8] = {};
  for (int k0 = 0; k0 < HH; k0 += 8){
    __syncthreads();
    float4 av = make_float4(0.f,0.f,0.f,0.f);
    if (aval) av = *(const float4*)(ap + k0 + akc);
    As[akc+0][ar] = av.x; As[akc+1][ar] = av.y; As[akc+2][ar] = av.z; As[akc+3][ar] = av.w;
    *(float4*)&Bs[bkr][bnc] = *(const float4*)(Wcat + (size_t)(k0 + bkr)*NE + n0 + bnc);
    __syncthreads();
    INNER8(As, Bs)
  }
  #pragma unroll
  for (int i = 0; i < 8; i++){
    int rr = Mb + ty*8 + i;
    if (rr < TT){
      float4 o0, o1;
      float t0v;
      t0v = c_[i][0] + bcat[n0+tx*8+0]; o0.x = t0v > 0.f ? t0v : expm1f(t0v);
      t0v = c_[i][1] + bcat[n0+tx*8+1]; o0.y = t0v > 0.f ? t0v : expm1f(t0v);
      t0v = c_[i][2] + bcat[n0+tx*8+2]; o0.z = t0v > 0.f ? t0v : expm1f(t0v);
      t0v = c_[i][3] + bcat[n0+tx*8+3]; o0.w = t0v > 0.f ? t0v : expm1f(t0v);
      t0v = c_[i][4] + bcat[n0+tx*8+4]; o1.x = t0v > 0.f ? t0v : expm1f(t0v);
      t0v = c_[i][5] + bcat[n0+tx*8+5]; o1.y = t0v > 0.f ? t0v : expm1f(t0v);
      t0v = c_[i][6] + bcat[n0+tx*8+6]; o1.z = t0v > 0.f ? t0v : expm1f(t0v);
      t0v = c_[i][7] + bcat[n0+tx*8+7]; o1.w = t0v > 0.f ? t0v : expm1f(t0v);
      *(float4*)&E[(size_t)rr*NE + n0 + tx*8] = o0;
      *(float4*)&E[(size_t)rr*NE + n0 + tx*8 + 4] = o1;
    }
  }
}

// ---------------- K2: T1 = enh @ ba_U ----------------
__global__ __launch_bounds__(256) void k_t1(const float* E, const float* baU, float* T1){
  __shared__ float As[8][132];
  __shared__ float Bs[8][132];
  int tid = threadIdx.x, tx = tid & 15, ty = tid >> 4;
  int Mb = blockIdx.x * 128, n0 = blockIdx.y * 128;
  int ar = tid >> 1, akc = (tid & 1) * 4;
  int row = Mb + ar;
  bool aval = row < TT;
  const float* ap = E + (size_t)(aval ? row : 0)*NE;
  int bkr = tid >> 5, bnc = (tid & 31) * 4;
  float c_[8][8] = {};
  for (int k0 = 0; k0 < 256; k0 += 8){
    __syncthreads();
    float4 av = make_float4(0.f,0.f,0.f,0.f);
    if (aval) av = *(const float4*)(ap + k0 + akc);
    As[akc+0][ar] = av.x; As[akc+1][ar] = av.y; As[akc+2][ar] = av.z; As[akc+3][ar] = av.w;
    *(float4*)&Bs[bkr][bnc] = *(const float4*)(baU + (size_t)(k0 + bkr)*256 + n0 + bnc);
    __syncthreads();
    INNER8(As, Bs)
  }
  #pragma unroll
  for (int i = 0; i < 8; i++){
    int rr = Mb + ty*8 + i;
    if (rr < TT){
      float4 o0 = {c_[i][0],c_[i][1],c_[i][2],c_[i][3]};
      float4 o1 = {c_[i][4],c_[i][5],c_[i][6],c_[i][7]};
      *(float4*)&T1[(size_t)rr*256 + n0 + tx*8] = o0;
      *(float4*)&T1[(size_t)rr*256 + n0 + tx*8 + 4] = o1;
    }
  }
}

// ---------------- K2b: dvec = enh@ba_Wd + ba_b ; evec = enm@ba_We ----------------
__global__ __launch_bounds__(256) void k_vecs(const float* E, const float* Wd,
    const float* We, const float* bab, float* dvec, float* evec){
  int w = threadIdx.x >> 6, lane = threadIdx.x & 63;
  int t = blockIdx.x*4 + w;
  const float* enh = E + (size_t)t*NE;
  const float* enm = enh + 256;
  float sd = 0.f, se = 0.f;
  for (int l = lane; l < 256; l += 64){ sd += enh[l]*Wd[l]; se += enm[l]*We[l]; }
  for (int o = 1; o < 64; o <<= 1){ sd += __shfl_xor(sd, o, 64); se += __shfl_xor(se, o, 64); }
  if (lane == 0){ dvec[t] = sd + bab[0]; evec[t] = se; }
}

// ---------------- K3a: S[b,h,m] = T1[b,h,:]·enm[b,m,:] + dvec[h] + evec[m] ----------
__global__ __launch_bounds__(256) void k_ns(const float* T1, const float* E,
    const float* dvec, const float* evec, float* S){
  __shared__ float As[8][132];
  __shared__ float Bs[8][132];
  int tid = threadIdx.x, tx = tid & 15, ty = tid >> 4;
  int b = blockIdx.y;
  int tm = blockIdx.x / 5, tn = blockIdx.x - tm*5;
  int Mb = tm*128, n0 = tn*128;
  int ar = tid >> 1, akc = (tid & 1) * 4;
  int hrow = Mb + ar; bool aval = hrow < L1;
  const float* ap = T1 + ((size_t)b*L1 + (aval ? hrow : 0))*256;
  int mrow = n0 + ar; bool bval = mrow < L1;
  const float* bp = E + ((size_t)b*L1 + (bval ? mrow : 0))*NE + 256;
  float c_[8][8] = {};
  for (int k0 = 0; k0 < 256; k0 += 8){
    __syncthreads();
    float4 av = make_float4(0.f,0.f,0.f,0.f);
    float4 bv2 = make_float4(0.f,0.f,0.f,0.f);
    if (aval) av = *(const float4*)(ap + k0 + akc);
    if (bval) bv2 = *(const float4*)(bp + k0 + akc);
    As[akc+0][ar] = av.x; As[akc+1][ar] = av.y; As[akc+2][ar] = av.z; As[akc+3][ar] = av.w;
    Bs[akc+0][ar] = bv2.x; Bs[akc+1][ar] = bv2.y; Bs[akc+2][ar] = bv2.z; Bs[akc+3][ar] = bv2.w;
    __syncthreads();
    INNER8(As, Bs)
  }
  float dr[8], er[8];
  #pragma unroll
  for (int i = 0; i < 8; i++){ int h = Mb + ty*8 + i; dr[i] = (h < L1) ? dvec[b*L1 + h] : 0.f; }
  #pragma unroll
  for (int j = 0; j < 8; j++){ int m = n0 + tx*8 + j; er[j] = (m < L1) ? evec[b*L1 + m] : 0.f; }
  float* Sb = S + (size_t)b*L1*L1;
  #pragma unroll
  for (int i = 0; i < 8; i++){
    int h = Mb + ty*8 + i;
    if (h < L1){
      #pragma unroll
      for (int j = 0; j < 8; j++){
        int m = n0 + tx*8 + j;
        if (m < L1) Sb[(size_t)h*L1 + m] = c_[i][j] + dr[i] + er[j];
      }
    }
  }
}

// --------- K3b: per-column log-softmax(gold) + node_nll + argmax decode -----------
__global__ __launch_bounds__(256) void k_nodecol(const float* S, const int* eh,
    const int* mask, float* out, int* idx){
  int b = blockIdx.y, mt = blockIdx.x;
  __shared__ float msk[L1];
  __shared__ float rM[8][32], rS[8][32], rG[8][32], rB[8][32];
  __shared__ int rH[8][32];
  __shared__ float npart[32];
  int tid = threadIdx.x; int c = tid & 31, r = tid >> 5;
  for (int h = tid; h < L1; h += 256) msk[h] = h ? (float)mask[b*LLEN + h - 1] : 0.f;
  __syncthreads();
  int m = mt*32 + c; bool valid = m < L1; int mc = valid ? m : (L1-1);
  float maskm = msk[mc];
  int gold = 0; if (valid && m) gold = eh[b*LLEN + m - 1];
  const float* Sb = S + (size_t)b*L1*L1;
  float Mx = -3.4e38f, Sm = 0.f, G = 0.f, Bv = -3.4e38f; int Bh = 0;
  for (int h = r; h < L1; h += 8){
    float s = Sb[(size_t)h*L1 + mc];
    float adj = s + ((msk[h] + maskm) > 1.5f ? 0.69314718055994531f : 0.f);
    float nm = fmaxf(Mx, adj);
    Sm = Sm * expf(Mx - nm) + expf(adj - nm);
    Mx = nm;
    if (h == gold) G = adj;
    float dv = (h == m) ? -3.4e38f : (s + (msk[h] > 0.5f ? 0.f : -1e8f));
    if (dv > Bv){ Bv = dv; Bh = h; }
  }
  rM[r][c] = Mx; rS[r][c] = Sm; rG[r][c] = G; rB[r][c] = Bv; rH[r][c] = Bh;
  __syncthreads();
  if (r == 0){
    float M0 = rM[0][c], S0 = rS[0][c], G0 = rG[0][c], B0 = rB[0][c]; int H0 = rH[0][c];
    for (int rr = 1; rr < 8; rr++){
      float m2 = rM[rr][c], s2 = rS[rr][c];
      float nm = fmaxf(M0, m2);
      S0 = S0*expf(M0 - nm) + s2*expf(m2 - nm); M0 = nm;
      G0 += rG[rr][c];
      float b2 = rB[rr][c]; int h2 = rH[rr][c];
      if (b2 > B0 || (b2 == B0 && h2 < H0)){ B0 = b2; H0 = h2; }
    }
    float nll = 0.f;
    if (valid && m >= 1) nll = (M0 + logf(S0)) - G0;
    npart[c] = nll;
    if (valid){
      idx[TT + b*L1 + m] = b*L1 + H0;
      if (m >= 1) out[b*LLEN + m - 1] = (float)H0;
    }
  }
  __syncthreads();
  if (tid == 0){
    float ssum = 0.f;
    for (int i2 = 0; i2 < 32; i2++) ssum += npart[i2];
    atomicAdd(out + 98368, ssum);
  }
}

// --------- K4: label bilinear as big-K MFMA GEMM, P generated on the fly ----------
// blocks 0..256 gold pass (label_nll), 257..513 pred pass (pred_lbl)
__global__ __launch_bounds__(256, 2) void k_label(const float* E, const unsigned short* WtTp,
    const int* idx, const int* labbuf, const float* lblb, float* out){
  __shared__ __align__(16) unsigned char Bst[2][8192];
  int tid = threadIdx.x;
  int w = tid >> 6, lane = tid & 63, c = lane & 15, q = lane >> 4;
  int bx = blockIdx.x;
  bool pred = bx >= 257;
  int t0 = (pred ? bx - 257 : bx) * 128;
  const float *yv[2], *xvv[2], *xsp[2];
  #pragma unroll
  for (int ms = 0; ms < 2; ms++){
    int tok = t0 + 32*w + 16*ms + c;
    int tc = tok < TT ? tok : 0;
    int g = idx[(pred ? TT : 0) + tc];
    yv[ms]  = E + (size_t)tc*NE + 640 + 8*q;
    xvv[ms] = E + (size_t)g*NE + 512 + 8*q;
    xsp[ms] = E + (size_t)g*NE + 512;
  }
  f32x4 acc[2][8];
  #pragma unroll
  for (int ms = 0; ms < 2; ms++)
    #pragma unroll
    for (int ns = 0; ns < 8; ns++){ acc[ms][ns][0]=0.f; acc[ms][ns][1]=0.f; acc[ms][ns][2]=0.f; acc[ms][ns][3]=0.f; }

  const char* gW = (const char*)WtTp;
  auto stage = [&](int s){
    #pragma unroll
    for (int i = 0; i < 2; i++){
      int f = w*128 + i*64 + lane;
      int n = f >> 2, kg = f & 3;
      const char* src = gW + (size_t)n*(KP*2) + (size_t)s*64 + kg*16;
      char* dst = (char*)&Bst[s & 1][f*16];
      __builtin_amdgcn_global_load_lds((gptr_t)src, (sptr_t)dst, 16, 0, 0);
    }
  };
  stage(0);
  int p = 0, d = 0;
  for (int s = 0; s < 520; s++){
    __syncthreads();
    if (s + 1 < 520) stage(s + 1);
    int e0 = p * 32;
    const char* bs = (const char*)Bst[s & 1];
    bf16x8 afr[2];
    #pragma unroll
    for (int ms = 0; ms < 2; ms++){
      const float* vb; float xsc;
      if (d < 128){ vb = yv[ms]; xsc = xsp[ms][d]; }
      else if (d == 128){ vb = xvv[ms]; xsc = 1.f; }
      else { vb = yv[ms]; xsc = 1.f; }
      float4 v0 = *(const float4*)(vb + e0);
      float4 v1 = *(const float4*)(vb + e0 + 4);
      union { unsigned u[4]; bf16x8 v; } uu;
      uu.u[0] = pk2(xsc*v0.x, xsc*v0.y);
      uu.u[1] = pk2(xsc*v0.z, xsc*v0.w);
      uu.u[2] = pk2(xsc*v1.x, xsc*v1.y);
      uu.u[3] = pk2(xsc*v1.z, xsc*v1.w);
      afr[ms] = uu.v;
    }
    #pragma unroll
    for (int ns = 0; ns < 8; ns++){
      bf16x8 bfr = *(const bf16x8*)(bs + ((ns*16 + c)*64 + q*16));
      acc[0][ns] = __builtin_amdgcn_mfma_f32_16x16x32_bf16(afr[0], bfr, acc[0][ns], 0, 0, 0);
      acc[1][ns] = __builtin_amdgcn_mfma_f32_16x16x32_bf16(afr[1], bfr, acc[1][ns], 0, 0, 0);
    }
    d++; if (d == 130){ d = 0; p++; }
  }
  // epilogue: C row = token (4q+i within subtile), col n = 16*ns + c
  float bv[8];
  #pragma unroll
  for (int ns = 0; ns < 8; ns++) bv[ns] = lblb[ns*16 + c];
  float part = 0.f;
  #pragma unroll
  for (int ms = 0; ms < 2; ms++){
    int tbase = t0 + 32*w + 16*ms + 4*q;
    float mx[4] = {-3.4e38f, -3.4e38f, -3.4e38f, -3.4e38f};
    #pragma unroll
    for (int ns = 0; ns < 8; ns++)
      #pragma unroll
      for (int i = 0; i < 4; i++){
        float v = acc[ms][ns][i] + bv[ns];
        mx[i] = fmaxf(mx[i], v);
      }
    #pragma unroll
    for (int o = 1; o < 16; o <<= 1)
      #pragma unroll
      for (int i = 0; i < 4; i++) mx[i] = fmaxf(mx[i], __shfl_xor(mx[i], o, 64));
    if (!pred){
      int lab[4];
      #pragma unroll
      for (int i = 0; i < 4; i++){ int t = tbase + i; lab[i] = labbuf[t < TT ? t : 0]; }
      float se[4] = {0.f,0.f,0.f,0.f}, gp[4] = {0.f,0.f,0.f,0.f};
      #pragma unroll
      for (int ns = 0; ns < 8; ns++)
        #pragma unroll
        for (int i = 0; i < 4; i++){
          float v = acc[ms][ns][i] + bv[ns];
          se[i] += expf(v - mx[i]);
          if (ns*16 + c == lab[i]) gp[i] += v;
        }
      #pragma unroll
      for (int o = 1; o < 16; o <<= 1)
        #pragma unroll
        for (int i = 0; i < 4; i++){ se[i] += __shfl_xor(se[i], o, 64); gp[i] += __shfl_xor(gp[i], o, 64); }
      if (c == 0){
        #pragma unroll
        for (int i = 0; i < 4; i++){
          int t = tbase + i;
          if (t < TT && (t % L1) != 0) part += mx[i] + logf(se[i]) - gp[i];
        }
      }
    } else {
      if (c == 0){
        #pragma unroll
        for (int i = 0; i < 4; i++){
          int t = tbase + i;
          if (t < TT){
            int mm = t % L1;
            if (mm) out[32768 + (t / L1)*LLEN + mm - 1] = mx[i];
          }
        }
      }
    }
  }
  if (!pred){
    for (int o = 1; o < 64; o <<= 1) part += __shfl_xor(part, o, 64);
    if (lane == 0) atomicAdd(out + 98369, part);
  }
}

extern "C" void kernel_launch(void* const* d_in, const int* in_sizes, int n_in,
                              void* d_out, int out_size, void* d_ws, size_t ws_size,
                              hipStream_t stream){
  const float* memory_bank = (const float*)d_in[0];
  const int* edge_heads = (const int*)d_in[1];
  const int* edge_labels = (const int*)d_in[2];
  const int* mask = (const int*)d_in[4];
  const float* sentinel = (const float*)d_in[5];
  const float* W_enh = (const float*)d_in[6];  const float* b_enh = (const float*)d_in[7];
  const float* W_enm = (const float*)d_in[8];  const float* b_enm = (const float*)d_in[9];
  const float* W_elh = (const float*)d_in[10]; const float* b_elh = (const float*)d_in[11];
  const float* W_elm = (const float*)d_in[12]; const float* b_elm = (const float*)d_in[13];
  const float* ba_U = (const float*)d_in[14];  const float* ba_Wd = (const float*)d_in[15];
  const float* ba_We = (const float*)d_in[16]; const float* ba_b = (const float*)d_in[17];
  const float* lbl_U = (const float*)d_in[18]; const float* lbl_Wl = (const float*)d_in[19];
  const float* lbl_Wr = (const float*)d_in[20]; const float* lbl_b = (const float*)d_in[21];
  float* out = (float*)d_out;

  char* wsc = (char*)d_ws;
  size_t o = 0;
  auto alloc = [&](size_t n){ o = (o + 255) & ~(size_t)255; void* pp = wsc + o; o += n; return pp; };
  float* E     = (float*)alloc((size_t)TT*NE*4);
  float* T1    = (float*)alloc((size_t)TT*256*4);
  float* S     = (float*)alloc((size_t)BB*L1*L1*4);
  float* Wcat  = (float*)alloc((size_t)HH*NE*4);
  float* bcat  = (float*)alloc((size_t)NE*4);
  unsigned short* WtTp = (unsigned short*)alloc((size_t)128*KP*2);
  float* dvec  = (float*)alloc((size_t)TT*4);
  float* evec  = (float*)alloc((size_t)TT*4);
  int*   idx   = (int*)alloc((size_t)2*TT*4);
  int*   labbuf= (int*)alloc((size_t)TT*4);

  k_init<<<dim3(129), 256, 0, stream>>>(edge_heads, edge_labels, out, idx, labbuf);
  k_wcat<<<dim3(1200), 256, 0, stream>>>(W_enh, b_enh, W_enm, b_enm, W_elh, b_elh, W_elm, b_elm, Wcat, bcat);
  k_wtt<<<dim3(65, 128), 256, 0, stream>>>(lbl_U, lbl_Wl, lbl_Wr, WtTp);
  k_enc<<<dim3(257, 6), 256, 0, stream>>>(memory_bank, sentinel, Wcat, bcat, E);
  k_t1<<<dim3(257, 2), 256, 0, stream>>>(E, ba_U, T1);
  k_vecs<<<dim3(8208), 256, 0, stream>>>(E, ba_Wd, ba_We, ba_b, dvec, evec);
  k_ns<<<dim3(25, 64), 256, 0, stream>>>(T1, E, dvec, evec, S);
  k_nodecol<<<dim3(17, 64), 256, 0, stream>>>(S, edge_heads, mask, out, idx);
  k_label<<<dim3(514), 256, 0, stream>>>(E, WtTp, idx, labbuf, lbl_b, out);
}

// Round 3
// 1195.136 us; speedup vs baseline: 1.6650x; 1.6650x over previous
//
#include <hip/hip_runtime.h>
#include <hip/hip_bf16.h>

#define BB 64
#define LLEN 512
#define HH 400
#define L1 513
#define TT 32832      // BB*L1
#define NE 768        // enh(256)|enm(256)|elh(128)|elm(128)
#define KP 16640      // 16384 bilinear + 128 Wl + 128 Wr (phase-permuted)
#define PHW 4160      // per-phase k' width: 130 d-slices * 32

typedef __attribute__((ext_vector_type(4))) float f32x4;
typedef __attribute__((ext_vector_type(8))) short bf16x8;
typedef unsigned int u32;
typedef __attribute__((address_space(1))) const u32* gptr_t;
typedef __attribute__((address_space(3))) u32* sptr_t;

// round-to-nearest-even f32 -> bf16 (finite inputs)
__device__ inline unsigned short f2bf(float x){
  unsigned u = __float_as_uint(x);
  unsigned r = (u + 0x7fffu + ((u >> 16) & 1u)) >> 16;
  return (unsigned short)r;
}
__device__ inline unsigned pk2(float a, float b){
  return (unsigned)f2bf(a) | ((unsigned)f2bf(b) << 16);
}
__device__ inline float bf2f(unsigned short h){
  return __uint_as_float(((unsigned)h) << 16);
}

// ---------------- init: labels1 output, gold gather idx, label buf, zero nll ----
__global__ __launch_bounds__(256) void k_init(const int* eh, const int* el, float* out,
                                              int* idx, int* labbuf){
  int t = blockIdx.x*256 + threadIdx.x;
  if (t < TT){
    int b = t / L1, m = t - b*L1;
    int lab = m ? el[b*LLEN + m - 1] : 0;
    int hd  = m ? eh[b*LLEN + m - 1] : 0;
    out[65536 + t] = (float)lab;
    labbuf[t] = lab;
    idx[t] = b*L1 + hd;
  }
  if (blockIdx.x == 0 && threadIdx.x < 2) out[98368 + threadIdx.x] = 0.f;
}

// ---------------- build concatenated encoder weights ----------------
__global__ __launch_bounds__(256) void k_wcat(const float* Wenh,const float* benh,
    const float* Wenm,const float* benm,const float* Welh,const float* belh,
    const float* Welm,const float* belm,float* Wcat,float* bcat){
  int g = blockIdx.x*256 + threadIdx.x;
  if (g < HH*NE){
    int k = g / NE, n = g - k*NE;
    float v;
    if (n < 256) v = Wenh[k*256 + n];
    else if (n < 512) v = Wenm[k*256 + n - 256];
    else if (n < 640) v = Welh[k*128 + n - 512];
    else v = Welm[k*128 + n - 640];
    Wcat[g] = v;
  }
  if (g < NE){
    float v;
    if (g < 256) v = benh[g];
    else if (g < 512) v = benm[g - 256];
    else if (g < 640) v = belh[g - 512];
    else v = belm[g - 640];
    bcat[g] = v;
  }
}

// ------------- build WtTp[n][k'] bf16, K phase-permuted: k' = p*4160 + d*32 + j,
// (p,d,j): d<128 -> U[n][d][32p+j]; d==128 -> Wl[n][32p+j]; d==129 -> Wr[n][32p+j]
__global__ __launch_bounds__(256) void k_wtt(const float* lblU, const float* Wl,
    const float* Wr, unsigned short* WtTp){
  int n = blockIdx.y;
  int kp = blockIdx.x*256 + threadIdx.x;
  if (kp >= KP) return;
  int p = kp / PHW; int q2 = kp - p*PHW; int dd = q2 >> 5; int j = q2 & 31; int e = p*32 + j;
  float v;
  if (dd < 128) v = lblU[(size_t)n*16384 + dd*128 + e];
  else if (dd == 128) v = Wl[n*128 + e];
  else v = Wr[n*128 + e];
  WtTp[(size_t)n*KP + kp] = f2bf(v);
}

#define INNER8(AS, BS) \
  _Pragma("unroll") \
  for (int kk = 0; kk < 8; kk++){ \
    float4 a0 = *(const float4*)&AS[kk][ty*8]; \
    float4 a1 = *(const float4*)&AS[kk][ty*8+4]; \
    float4 b0 = *(const float4*)&BS[kk][tx*8]; \
    float4 b1 = *(const float4*)&BS[kk][tx*8+4]; \
    float avv[8] = {a0.x,a0.y,a0.z,a0.w,a1.x,a1.y,a1.z,a1.w}; \
    float bvv[8] = {b0.x,b0.y,b0.z,b0.w,b1.x,b1.y,b1.z,b1.w}; \
    _Pragma("unroll") \
    for (int ii = 0; ii < 8; ii++) \
      _Pragma("unroll") \
      for (int jj = 0; jj < 8; jj++) \
        c_[ii][jj] += avv[ii]*bvv[jj]; \
  }

// ---------------- K1: E = elu([sentinel;mb] @ Wcat + bcat), fp32 128x128x8 tile ----
__global__ __launch_bounds__(256) void k_enc(const float* mb, const float* sent,
    const float* Wcat, const float* bcat, float* E){
  __shared__ float As[8][132];
  __shared__ float Bs[8][132];
  int tid = threadIdx.x, tx = tid & 15, ty = tid >> 4;
  int Mb = blockIdx.x * 128, n0 = blockIdx.y * 128;
  int ar = tid >> 1, akc = (tid & 1) * 4;
  int row = Mb + ar;
  bool aval = row < TT;
  const float* ap = sent;
  if (aval){
    int br = row / L1, mr = row - br*L1;
    if (mr) ap = mb + (size_t)(br*LLEN + mr - 1)*HH;
  }
  int bkr = tid >> 5, bnc = (tid & 31) * 4;
  float c_[8][8] = {};
  for (int k0 = 0; k0 < HH; k0 += 8){
    __syncthreads();
    float4 av = make_float4(0.f,0.f,0.f,0.f);
    if (aval) av = *(const float4*)(ap + k0 + akc);
    As[akc+0][ar] = av.x; As[akc+1][ar] = av.y; As[akc+2][ar] = av.z; As[akc+3][ar] = av.w;
    *(float4*)&Bs[bkr][bnc] = *(const float4*)(Wcat + (size_t)(k0 + bkr)*NE + n0 + bnc);
    __syncthreads();
    INNER8(As, Bs)
  }
  #pragma unroll
  for (int i = 0; i < 8; i++){
    int rr = Mb + ty*8 + i;
    if (rr < TT){
      float4 o0, o1;
      float t0v;
      t0v = c_[i][0] + bcat[n0+tx*8+0]; o0.x = t0v > 0.f ? t0v : expm1f(t0v);
      t0v = c_[i][1] + bcat[n0+tx*8+1]; o0.y = t0v > 0.f ? t0v : expm1f(t0v);
      t0v = c_[i][2] + bcat[n0+tx*8+2]; o0.z = t0v > 0.f ? t0v : expm1f(t0v);
      t0v = c_[i][3] + bcat[n0+tx*8+3]; o0.w = t0v > 0.f ? t0v : expm1f(t0v);
      t0v = c_[i][4] + bcat[n0+tx*8+4]; o1.x = t0v > 0.f ? t0v : expm1f(t0v);
      t0v = c_[i][5] + bcat[n0+tx*8+5]; o1.y = t0v > 0.f ? t0v : expm1f(t0v);
      t0v = c_[i][6] + bcat[n0+tx*8+6]; o1.z = t0v > 0.f ? t0v : expm1f(t0v);
      t0v = c_[i][7] + bcat[n0+tx*8+7]; o1.w = t0v > 0.f ? t0v : expm1f(t0v);
      *(float4*)&E[(size_t)rr*NE + n0 + tx*8] = o0;
      *(float4*)&E[(size_t)rr*NE + n0 + tx*8 + 4] = o1;
    }
  }
}

// ---------------- K2: T1 = enh @ ba_U ----------------
__global__ __launch_bounds__(256) void k_t1(const float* E, const float* baU, float* T1){
  __shared__ float As[8][132];
  __shared__ float Bs[8][132];
  int tid = threadIdx.x, tx = tid & 15, ty = tid >> 4;
  int Mb = blockIdx.x * 128, n0 = blockIdx.y * 128;
  int ar = tid >> 1, akc = (tid & 1) * 4;
  int row = Mb + ar;
  bool aval = row < TT;
  const float* ap = E + (size_t)(aval ? row : 0)*NE;
  int bkr = tid >> 5, bnc = (tid & 31) * 4;
  float c_[8][8] = {};
  for (int k0 = 0; k0 < 256; k0 += 8){
    __syncthreads();
    float4 av = make_float4(0.f,0.f,0.f,0.f);
    if (aval) av = *(const float4*)(ap + k0 + akc);
    As[akc+0][ar] = av.x; As[akc+1][ar] = av.y; As[akc+2][ar] = av.z; As[akc+3][ar] = av.w;
    *(float4*)&Bs[bkr][bnc] = *(const float4*)(baU + (size_t)(k0 + bkr)*256 + n0 + bnc);
    __syncthreads();
    INNER8(As, Bs)
  }
  #pragma unroll
  for (int i = 0; i < 8; i++){
    int rr = Mb + ty*8 + i;
    if (rr < TT){
      float4 o0 = {c_[i][0],c_[i][1],c_[i][2],c_[i][3]};
      float4 o1 = {c_[i][4],c_[i][5],c_[i][6],c_[i][7]};
      *(float4*)&T1[(size_t)rr*256 + n0 + tx*8] = o0;
      *(float4*)&T1[(size_t)rr*256 + n0 + tx*8 + 4] = o1;
    }
  }
}

// ---------------- K2b: dvec = enh@ba_Wd + ba_b ; evec = enm@ba_We ----------------
__global__ __launch_bounds__(256) void k_vecs(const float* E, const float* Wd,
    const float* We, const float* bab, float* dvec, float* evec){
  int w = threadIdx.x >> 6, lane = threadIdx.x & 63;
  int t = blockIdx.x*4 + w;
  const float* enh = E + (size_t)t*NE;
  const float* enm = enh + 256;
  float sd = 0.f, se = 0.f;
  for (int l = lane; l < 256; l += 64){ sd += enh[l]*Wd[l]; se += enm[l]*We[l]; }
  for (int o = 1; o < 64; o <<= 1){ sd += __shfl_xor(sd, o, 64); se += __shfl_xor(se, o, 64); }
  if (lane == 0){ dvec[t] = sd + bab[0]; evec[t] = se; }
}

// ---------------- K3a: S[b,h,m] = T1[b,h,:]·enm[b,m,:] + dvec[h] + evec[m] ----------
__global__ __launch_bounds__(256) void k_ns(const float* T1, const float* E,
    const float* dvec, const float* evec, float* S){
  __shared__ float As[8][132];
  __shared__ float Bs[8][132];
  int tid = threadIdx.x, tx = tid & 15, ty = tid >> 4;
  int b = blockIdx.y;
  int tm = blockIdx.x / 5, tn = blockIdx.x - tm*5;
  int Mb = tm*128, n0 = tn*128;
  int ar = tid >> 1, akc = (tid & 1) * 4;
  int hrow = Mb + ar; bool aval = hrow < L1;
  const float* ap = T1 + ((size_t)b*L1 + (aval ? hrow : 0))*256;
  int mrow = n0 + ar; bool bval = mrow < L1;
  const float* bp = E + ((size_t)b*L1 + (bval ? mrow : 0))*NE + 256;
  float c_[8][8] = {};
  for (int k0 = 0; k0 < 256; k0 += 8){
    __syncthreads();
    float4 av = make_float4(0.f,0.f,0.f,0.f);
    float4 bv2 = make_float4(0.f,0.f,0.f,0.f);
    if (aval) av = *(const float4*)(ap + k0 + akc);
    if (bval) bv2 = *(const float4*)(bp + k0 + akc);
    As[akc+0][ar] = av.x; As[akc+1][ar] = av.y; As[akc+2][ar] = av.z; As[akc+3][ar] = av.w;
    Bs[akc+0][ar] = bv2.x; Bs[akc+1][ar] = bv2.y; Bs[akc+2][ar] = bv2.z; Bs[akc+3][ar] = bv2.w;
    __syncthreads();
    INNER8(As, Bs)
  }
  float dr[8], er[8];
  #pragma unroll
  for (int i = 0; i < 8; i++){ int h = Mb + ty*8 + i; dr[i] = (h < L1) ? dvec[b*L1 + h] : 0.f; }
  #pragma unroll
  for (int j = 0; j < 8; j++){ int m = n0 + tx*8 + j; er[j] = (m < L1) ? evec[b*L1 + m] : 0.f; }
  float* Sb = S + (size_t)b*L1*L1;
  #pragma unroll
  for (int i = 0; i < 8; i++){
    int h = Mb + ty*8 + i;
    if (h < L1){
      #pragma unroll
      for (int j = 0; j < 8; j++){
        int m = n0 + tx*8 + j;
        if (m < L1) Sb[(size_t)h*L1 + m] = c_[i][j] + dr[i] + er[j];
      }
    }
  }
}

// --------- K3b: per-column log-softmax(gold) + node_nll + argmax decode -----------
__global__ __launch_bounds__(256) void k_nodecol(const float* S, const int* eh,
    const int* mask, float* out, int* idx){
  int b = blockIdx.y, mt = blockIdx.x;
  __shared__ float msk[L1];
  __shared__ float rM[8][32], rS[8][32], rG[8][32], rB[8][32];
  __shared__ int rH[8][32];
  __shared__ float npart[32];
  int tid = threadIdx.x; int c = tid & 31, r = tid >> 5;
  for (int h = tid; h < L1; h += 256) msk[h] = h ? (float)mask[b*LLEN + h - 1] : 0.f;
  __syncthreads();
  int m = mt*32 + c; bool valid = m < L1; int mc = valid ? m : (L1-1);
  float maskm = msk[mc];
  int gold = 0; if (valid && m) gold = eh[b*LLEN + m - 1];
  const float* Sb = S + (size_t)b*L1*L1;
  float Mx = -3.4e38f, Sm = 0.f, G = 0.f, Bv = -3.4e38f; int Bh = 0;
  for (int h = r; h < L1; h += 8){
    float s = Sb[(size_t)h*L1 + mc];
    float adj = s + ((msk[h] + maskm) > 1.5f ? 0.69314718055994531f : 0.f);
    float nm = fmaxf(Mx, adj);
    Sm = Sm * expf(Mx - nm) + expf(adj - nm);
    Mx = nm;
    if (h == gold) G = adj;
    float dv = (h == m) ? -3.4e38f : (s + (msk[h] > 0.5f ? 0.f : -1e8f));
    if (dv > Bv){ Bv = dv; Bh = h; }
  }
  rM[r][c] = Mx; rS[r][c] = Sm; rG[r][c] = G; rB[r][c] = Bv; rH[r][c] = Bh;
  __syncthreads();
  if (r == 0){
    float M0 = rM[0][c], S0 = rS[0][c], G0 = rG[0][c], B0 = rB[0][c]; int H0 = rH[0][c];
    for (int rr = 1; rr < 8; rr++){
      float m2 = rM[rr][c], s2 = rS[rr][c];
      float nm = fmaxf(M0, m2);
      S0 = S0*expf(M0 - nm) + s2*expf(m2 - nm); M0 = nm;
      G0 += rG[rr][c];
      float b2 = rB[rr][c]; int h2 = rH[rr][c];
      if (b2 > B0 || (b2 == B0 && h2 < H0)){ B0 = b2; H0 = h2; }
    }
    float nll = 0.f;
    if (valid && m >= 1) nll = (M0 + logf(S0)) - G0;
    npart[c] = nll;
    if (valid){
      idx[TT + b*L1 + m] = b*L1 + H0;
      if (m >= 1) out[b*LLEN + m - 1] = (float)H0;
    }
  }
  __syncthreads();
  if (tid == 0){
    float ssum = 0.f;
    for (int i2 = 0; i2 < 32; i2++) ssum += npart[i2];
    atomicAdd(out + 98368, ssum);
  }
}

// --------- K4: label bilinear as big-K MFMA GEMM, P generated on the fly ----------
// blocks 0..256 gold pass (label_nll), 257..513 pred pass (pred_lbl)
// v2: x staged in LDS (bf16, conflict-free), y hoisted per phase into regs,
//     B LDS layout lane-contiguous (conflict-free ds_read_b128).
__global__ __launch_bounds__(256, 2) void k_label(const float* E, const unsigned short* WtTp,
    const int* idx, const int* labbuf, const float* lblb, float* out){
  __shared__ __align__(16) unsigned char Bst[2][8192];
  __shared__ unsigned int xls[128*65];  // 128 tokens x 130 bf16 (stride 65 u32 kills conflicts)
  int tid = threadIdx.x;
  int w = tid >> 6, lane = tid & 63, c = lane & 15, q = lane >> 4;
  int bx = blockIdx.x;
  bool pred = bx >= 257;
  int t0 = (pred ? bx - 257 : bx) * 128;

  // ---- stage gathered x rows (elh[g]) into LDS as bf16, once per block ----
  {
    int tok = tid >> 1, half = tid & 1;
    int tg = t0 + tok; int tc = tg < TT ? tg : 0;
    int g = idx[(pred ? TT : 0) + tc];
    const float* xr = E + (size_t)g*NE + 512 + half*64;
    unsigned* dstx = &xls[tok*65 + half*32];
    #pragma unroll
    for (int j = 0; j < 16; j++){
      float4 v = *(const float4*)(xr + j*4);
      dstx[2*j]   = pk2(v.x, v.y);
      dstx[2*j+1] = pk2(v.z, v.w);
    }
  }

  const float *yvb[2], *xvb[2];
  int tokl[2];
  #pragma unroll
  for (int ms = 0; ms < 2; ms++){
    int tok = t0 + 32*w + 16*ms + c;
    int tc = tok < TT ? tok : 0;
    int g = idx[(pred ? TT : 0) + tc];
    yvb[ms] = E + (size_t)tc*NE + 640 + 8*q;   // elm row, this lane's q-offset
    xvb[ms] = E + (size_t)g*NE + 512 + 8*q;    // elh row (gathered)
    tokl[ms] = 32*w + 16*ms + c;               // token index within block
  }
  f32x4 acc[2][8];
  #pragma unroll
  for (int ms = 0; ms < 2; ms++)
    #pragma unroll
    for (int ns = 0; ns < 8; ns++){ acc[ms][ns][0]=0.f; acc[ms][ns][1]=0.f; acc[ms][ns][2]=0.f; acc[ms][ns][3]=0.f; }

  const char* gW = (const char*)WtTp;
  // stage B slice s into Bst[s&1]: chunk f holds WtTp[(f>>6)*16 + (f&15)][s*32 + ((f>>4)&3)*8 ..+8)
  auto stage = [&](int s){
    #pragma unroll
    for (int i = 0; i < 2; i++){
      int f = w*128 + i*64 + lane;
      int n = ((f >> 6) << 4) + (f & 15);
      int kq = (f >> 4) & 3;
      const char* src = gW + (size_t)n*(KP*2) + (size_t)s*64 + kq*16;
      char* dst = (char*)&Bst[s & 1][f*16];
      __builtin_amdgcn_global_load_lds((gptr_t)src, (sptr_t)dst, 16, 0, 0);
    }
  };
  stage(0);
  const unsigned short* xsh = (const unsigned short*)xls;
  float yreg[2][8];
  unsigned ypk[2][4], xpk[2][4];
  int p = 0, d = 0;
  for (int s = 0; s < 520; s++){
    __syncthreads();
    if (s + 1 < 520) stage(s + 1);
    if (d == 0){
      int e0 = p * 32;
      #pragma unroll
      for (int ms = 0; ms < 2; ms++){
        float4 v0 = *(const float4*)(yvb[ms] + e0);
        float4 v1 = *(const float4*)(yvb[ms] + e0 + 4);
        yreg[ms][0]=v0.x; yreg[ms][1]=v0.y; yreg[ms][2]=v0.z; yreg[ms][3]=v0.w;
        yreg[ms][4]=v1.x; yreg[ms][5]=v1.y; yreg[ms][6]=v1.z; yreg[ms][7]=v1.w;
        ypk[ms][0]=pk2(v0.x,v0.y); ypk[ms][1]=pk2(v0.z,v0.w);
        ypk[ms][2]=pk2(v1.x,v1.y); ypk[ms][3]=pk2(v1.z,v1.w);
        float4 u0 = *(const float4*)(xvb[ms] + e0);
        float4 u1 = *(const float4*)(xvb[ms] + e0 + 4);
        xpk[ms][0]=pk2(u0.x,u0.y); xpk[ms][1]=pk2(u0.z,u0.w);
        xpk[ms][2]=pk2(u1.x,u1.y); xpk[ms][3]=pk2(u1.z,u1.w);
      }
    }
    const char* bs = (const char*)Bst[s & 1];
    bf16x8 afr[2];
    if (d < 128){
      #pragma unroll
      for (int ms = 0; ms < 2; ms++){
        float xsc = bf2f(xsh[tokl[ms]*130 + d]);
        union { unsigned u[4]; bf16x8 v; } uu;
        uu.u[0] = pk2(xsc*yreg[ms][0], xsc*yreg[ms][1]);
        uu.u[1] = pk2(xsc*yreg[ms][2], xsc*yreg[ms][3]);
        uu.u[2] = pk2(xsc*yreg[ms][4], xsc*yreg[ms][5]);
        uu.u[3] = pk2(xsc*yreg[ms][6], xsc*yreg[ms][7]);
        afr[ms] = uu.v;
      }
    } else if (d == 128){
      #pragma unroll
      for (int ms = 0; ms < 2; ms++){
        union { unsigned u[4]; bf16x8 v; } uu;
        uu.u[0]=xpk[ms][0]; uu.u[1]=xpk[ms][1]; uu.u[2]=xpk[ms][2]; uu.u[3]=xpk[ms][3];
        afr[ms] = uu.v;
      }
    } else {
      #pragma unroll
      for (int ms = 0; ms < 2; ms++){
        union { unsigned u[4]; bf16x8 v; } uu;
        uu.u[0]=ypk[ms][0]; uu.u[1]=ypk[ms][1]; uu.u[2]=ypk[ms][2]; uu.u[3]=ypk[ms][3];
        afr[ms] = uu.v;
      }
    }
    #pragma unroll
    for (int ns = 0; ns < 8; ns++){
      bf16x8 bfr = *(const bf16x8*)(bs + ns*1024 + lane*16);
      acc[0][ns] = __builtin_amdgcn_mfma_f32_16x16x32_bf16(afr[0], bfr, acc[0][ns], 0, 0, 0);
      acc[1][ns] = __builtin_amdgcn_mfma_f32_16x16x32_bf16(afr[1], bfr, acc[1][ns], 0, 0, 0);
    }
    d++; if (d == 130){ d = 0; p++; }
  }
  // epilogue: C row = token (4q+i within subtile), col n = 16*ns + c
  float bv[8];
  #pragma unroll
  for (int ns = 0; ns < 8; ns++) bv[ns] = lblb[ns*16 + c];
  float part = 0.f;
  #pragma unroll
  for (int ms = 0; ms < 2; ms++){
    int tbase = t0 + 32*w + 16*ms + 4*q;
    float mx[4] = {-3.4e38f, -3.4e38f, -3.4e38f, -3.4e38f};
    #pragma unroll
    for (int ns = 0; ns < 8; ns++)
      #pragma unroll
      for (int i = 0; i < 4; i++){
        float v = acc[ms][ns][i] + bv[ns];
        mx[i] = fmaxf(mx[i], v);
      }
    #pragma unroll
    for (int o = 1; o < 16; o <<= 1)
      #pragma unroll
      for (int i = 0; i < 4; i++) mx[i] = fmaxf(mx[i], __shfl_xor(mx[i], o, 64));
    if (!pred){
      int lab[4];
      #pragma unroll
      for (int i = 0; i < 4; i++){ int t = tbase + i; lab[i] = labbuf[t < TT ? t : 0]; }
      float se[4] = {0.f,0.f,0.f,0.f}, gp[4] = {0.f,0.f,0.f,0.f};
      #pragma unroll
      for (int ns = 0; ns < 8; ns++)
        #pragma unroll
        for (int i = 0; i < 4; i++){
          float v = acc[ms][ns][i] + bv[ns];
          se[i] += expf(v - mx[i]);
          if (ns*16 + c == lab[i]) gp[i] += v;
        }
      #pragma unroll
      for (int o = 1; o < 16; o <<= 1)
        #pragma unroll
        for (int i = 0; i < 4; i++){ se[i] += __shfl_xor(se[i], o, 64); gp[i] += __shfl_xor(gp[i], o, 64); }
      if (c == 0){
        #pragma unroll
        for (int i = 0; i < 4; i++){
          int t = tbase + i;
          if (t < TT && (t % L1) != 0) part += mx[i] + logf(se[i]) - gp[i];
        }
      }
    } else {
      if (c == 0){
        #pragma unroll
        for (int i = 0; i < 4; i++){
          int t = tbase + i;
          if (t < TT){
            int mm = t % L1;
            if (mm) out[32768 + (t / L1)*LLEN + mm - 1] = mx[i];
          }
        }
      }
    }
  }
  if (!pred){
    for (int o = 1; o < 64; o <<= 1) part += __shfl_xor(part, o, 64);
    if (lane == 0) atomicAdd(out + 98369, part);
  }
}

extern "C" void kernel_launch(void* const* d_in, const int* in_sizes, int n_in,
                              void* d_out, int out_size, void* d_ws, size_t ws_size,
                              hipStream_t stream){
  const float* memory_bank = (const float*)d_in[0];
  const int* edge_heads = (const int*)d_in[1];
  const int* edge_labels = (const int*)d_in[2];
  const int* mask = (const int*)d_in[4];
  const float* sentinel = (const float*)d_in[5];
  const float* W_enh = (const float*)d_in[6];  const float* b_enh = (const float*)d_in[7];
  const float* W_enm = (const float*)d_in[8];  const float* b_enm = (const float*)d_in[9];
  const float* W_elh = (const float*)d_in[10]; const float* b_elh = (const float*)d_in[11];
  const float* W_elm = (const float*)d_in[12]; const float* b_elm = (const float*)d_in[13];
  const float* ba_U = (const float*)d_in[14];  const float* ba_Wd = (const float*)d_in[15];
  const float* ba_We = (const float*)d_in[16]; const float* ba_b = (const float*)d_in[17];
  const float* lbl_U = (const float*)d_in[18]; const float* lbl_Wl = (const float*)d_in[19];
  const float* lbl_Wr = (const float*)d_in[20]; const float* lbl_b = (const float*)d_in[21];
  float* out = (float*)d_out;

  char* wsc = (char*)d_ws;
  size_t o = 0;
  auto alloc = [&](size_t n){ o = (o + 255) & ~(size_t)255; void* pp = wsc + o; o += n; return pp; };
  float* E     = (float*)alloc((size_t)TT*NE*4);
  float* T1    = (float*)alloc((size_t)TT*256*4);
  float* S     = (float*)alloc((size_t)BB*L1*L1*4);
  float* Wcat  = (float*)alloc((size_t)HH*NE*4);
  float* bcat  = (float*)alloc((size_t)NE*4);
  unsigned short* WtTp = (unsigned short*)alloc((size_t)128*KP*2);
  float* dvec  = (float*)alloc((size_t)TT*4);
  float* evec  = (float*)alloc((size_t)TT*4);
  int*   idx   = (int*)alloc((size_t)2*TT*4);
  int*   labbuf= (int*)alloc((size_t)TT*4);

  k_init<<<dim3(129), 256, 0, stream>>>(edge_heads, edge_labels, out, idx, labbuf);
  k_wcat<<<dim3(1200), 256, 0, stream>>>(W_enh, b_enh, W_enm, b_enm, W_elh, b_elh, W_elm, b_elm, Wcat, bcat);
  k_wtt<<<dim3(65, 128), 256, 0, stream>>>(lbl_U, lbl_Wl, lbl_Wr, WtTp);
  k_enc<<<dim3(257, 6), 256, 0, stream>>>(memory_bank, sentinel, Wcat, bcat, E);
  k_t1<<<dim3(257, 2), 256, 0, stream>>>(E, ba_U, T1);
  k_vecs<<<dim3(8208), 256, 0, stream>>>(E, ba_Wd, ba_We, ba_b, dvec, evec);
  k_ns<<<dim3(25, 64), 256, 0, stream>>>(T1, E, dvec, evec, S);
  k_nodecol<<<dim3(17, 64), 256, 0, stream>>>(S, edge_heads, mask, out, idx);
  k_label<<<dim3(514), 256, 0, stream>>>(E, WtTp, idx, labbuf, lbl_b, out);
}